// Round 6
// baseline (28231.277 us; speedup 1.0000x reference)
//
#include <hip/hip_runtime.h>
#include <hip/hip_bf16.h>

#define D_NODE 300
#define DHID   600
#define NLAYER 5
#define NG     8192
#define BN_EPS 1e-5f
#define CHUNK  8192    // MLP row-chunk

typedef unsigned short u16;
typedef unsigned long long u64;

// ---- bf16 helpers (RNE) ----
__device__ __forceinline__ float bf2f(u16 u) {
    union { unsigned int i; float f; } v; v.i = ((unsigned int)u) << 16; return v.f;
}
__device__ __forceinline__ u16 f2bf(float f) {
    union { float f; unsigned int i; } v; v.f = f;
    unsigned int x = v.i;
    return (u16)((x + 0x7FFFu + ((x >> 16) & 1u)) >> 16);
}

// packed 4x bf16 atomic add via 64-bit CAS (each thread owns an aligned quad)
__device__ __forceinline__ void atomic_add_bf16x4(u64* p, float a0, float a1, float a2, float a3)
{
    u64 old = *p;
    while (true) {
        u64 assumed = old;
        u16 e0 = (u16)(assumed & 0xFFFFull);
        u16 e1 = (u16)((assumed >> 16) & 0xFFFFull);
        u16 e2 = (u16)((assumed >> 32) & 0xFFFFull);
        u16 e3 = (u16)((assumed >> 48) & 0xFFFFull);
        u64 nw = (u64)f2bf(bf2f(e0) + a0)
               | ((u64)f2bf(bf2f(e1) + a1) << 16)
               | ((u64)f2bf(bf2f(e2) + a2) << 32)
               | ((u64)f2bf(bf2f(e3) + a3) << 48);
        old = atomicCAS(p, assumed, nw);
        if (old == assumed) break;
    }
}

// ---------------- embed: h(bf16) = emb_atom[an] + emb_chir[ct]  (f32 tables) ----------------
__global__ __launch_bounds__(256) void embed_kernel(
    const int* __restrict__ an, const int* __restrict__ ct,
    const float* __restrict__ emb_atom, const float* __restrict__ emb_chir,
    u16* __restrict__ h, long total)
{
    long idx = (long)blockIdx.x * blockDim.x + threadIdx.x;
    if (idx >= total) return;
    int n = (int)(idx / 75);
    int c = (int)(idx % 75);
    int a = an[n], cc = ct[n];
    const float4 av = *(const float4*)&emb_atom[(long)a * D_NODE + c * 4];
    const float4 cv = *(const float4*)&emb_chir[(long)cc * D_NODE + c * 4];
    ushort4 o;
    o.x = f2bf(av.x + cv.x);
    o.y = f2bf(av.y + cv.y);
    o.z = f2bf(av.z + cv.z);
    o.w = f2bf(av.w + cv.w);
    *(ushort4*)&h[(long)n * D_NODE + c * 4] = o;
}

// ---------------- z = h (64-bit copy; init for scatter z = h + agg) ----------------
__global__ __launch_bounds__(256) void zcopy_kernel(
    const u64* __restrict__ in, u64* __restrict__ out, long n8)
{
    long i = (long)blockIdx.x * blockDim.x + threadIdx.x;
    if (i < n8) out[i] = in[i];
}

// ---------------- edge scatter: z[dst] += h[src] + ebond[bt] + edir[bd] ----------------
__global__ __launch_bounds__(256) void edge_scatter(
    const u16* __restrict__ h,
    const int* __restrict__ src, const int* __restrict__ dst,
    const int* __restrict__ bt, const int* __restrict__ bd,
    const float* __restrict__ ebond, const float* __restrict__ edir,
    u16* __restrict__ z, long total)
{
    long idx = (long)blockIdx.x * blockDim.x + threadIdx.x;
    if (idx >= total) return;
    int e = (int)(idx / 75);
    int c = (int)(idx % 75);
    int s = src[e], d = dst[e];
    const ushort4 hv = *(const ushort4*)&h[(long)s * D_NODE + c * 4];
    const float4 bv = *(const float4*)&ebond[(long)bt[e] * D_NODE + c * 4];
    const float4 dv = *(const float4*)&edir[(long)bd[e] * D_NODE + c * 4];
    u64* zp = (u64*)&z[(long)d * D_NODE + c * 4];
    atomic_add_bf16x4(zp,
        bf2f(hv.x) + bv.x + dv.x,
        bf2f(hv.y) + bv.y + dv.y,
        bf2f(hv.z) + bv.z + dv.z,
        bf2f(hv.w) + bv.w + dv.w);
}

// ---------------- tiled f32 GEMM (bf16 A, f32 W), fused epilogue, bf16 out ----------------
// MODE 0: out = relu(A@W + bias). MODE 1: out = BN(A@W + bias), optional relu.
template<int MODE>
__global__ __launch_bounds__(256) void gemm_fused(
    const u16* __restrict__ A, const float* __restrict__ W,
    const float* __restrict__ bias,
    const float* __restrict__ bn_g, const float* __restrict__ bn_b,
    const float* __restrict__ bn_m, const float* __restrict__ bn_v,
    u16* __restrict__ out, int M, int K, int N, int do_relu)
{
    __shared__ float As[16][65];
    __shared__ float Bs[16][64];
    const int bm = blockIdx.y * 64;
    const int bn = blockIdx.x * 64;
    const int tid = threadIdx.x;
    const int tx = tid % 16, ty = tid / 16;

    float acc[4][4] = {};

    for (int k0 = 0; k0 < K; k0 += 16) {
        #pragma unroll
        for (int r = 0; r < 4; ++r) {
            int row = ty + r * 16;
            int gm = bm + row, gk = k0 + tx;
            float v = 0.f;
            if (gm < M && gk < K) v = bf2f(A[(long)gm * K + gk]);
            As[tx][row] = v;
        }
        #pragma unroll
        for (int r = 0; r < 4; ++r) {
            int kk = tid / 64 + r * 4;
            int nn = tid % 64;
            int gk = k0 + kk, gn = bn + nn;
            float v = 0.f;
            if (gk < K && gn < N) v = W[(long)gk * N + gn];
            Bs[kk][nn] = v;
        }
        __syncthreads();
        #pragma unroll
        for (int kk = 0; kk < 16; ++kk) {
            float a[4], b[4];
            #pragma unroll
            for (int i = 0; i < 4; ++i) a[i] = As[kk][ty * 4 + i];
            #pragma unroll
            for (int j = 0; j < 4; ++j) b[j] = Bs[kk][tx * 4 + j];
            #pragma unroll
            for (int i = 0; i < 4; ++i)
                #pragma unroll
                for (int j = 0; j < 4; ++j)
                    acc[i][j] += a[i] * b[j];
        }
        __syncthreads();
    }

    #pragma unroll
    for (int i = 0; i < 4; ++i) {
        int gm = bm + ty * 4 + i;
        if (gm >= M) continue;
        #pragma unroll
        for (int j = 0; j < 4; ++j) {
            int gn = bn + tx * 4 + j;
            if (gn >= N) continue;
            float v = acc[i][j] + bias[gn];
            if (MODE == 1) {
                float sc = bn_g[gn] * rsqrtf(bn_v[gn] + BN_EPS);
                v = (v - bn_m[gn]) * sc + bn_b[gn];
            }
            if (do_relu) v = fmaxf(v, 0.f);
            out[(long)gm * N + gn] = f2bf(v);
        }
    }
}

// ---------------- fused pool (sorted gid, binary search) + Linear(300,256) ----------------
__device__ __forceinline__ int lower_bound(const int* __restrict__ a, int n, int key)
{
    int lo = 0, hi = n;
    while (lo < hi) { int mid = (lo + hi) >> 1; if (a[mid] < key) lo = mid + 1; else hi = mid; }
    return lo;
}

__global__ __launch_bounds__(256) void pool_head1(
    const u16* __restrict__ h, const int* __restrict__ gid, int N,
    const float* __restrict__ Wt, const float* __restrict__ bt,
    u16* __restrict__ x1)
{
    __shared__ float xs[304];
    __shared__ int se[2];
    int g = blockIdx.x;
    int t = threadIdx.x;   // 0..255
    if (t == 0) se[0] = lower_bound(gid, N, g);
    if (t == 1) se[1] = lower_bound(gid, N, g + 1);
    __syncthreads();
    int start = se[0], end = se[1];
    float inv = (end > start) ? 1.0f / (float)(end - start) : 0.f;  // cnt=0 -> x=0
    float a0 = 0.f, a1 = 0.f;
    for (int n = start; n < end; ++n) {
        const u16* hp = &h[(long)n * D_NODE];
        a0 += bf2f(hp[t]);
        if (t < 44) a1 += bf2f(hp[256 + t]);
    }
    xs[t] = a0 * inv;
    if (t < 44) xs[256 + t] = a1 * inv;
    __syncthreads();
    float acc = bt[t];
    for (int k = 0; k < D_NODE; ++k)
        acc = fmaf(xs[k], Wt[(long)k * 256 + t], acc);
    x1[(long)g * 256 + t] = f2bf(acc);
}

// ---------------- head part 2: Linear(256,128)+leaky, Linear(128,1), f32 out ----------------
__global__ __launch_bounds__(128) void head2_kernel(
    const u16* __restrict__ x1,
    const float* __restrict__ Wh, const float* __restrict__ bh,
    const float* __restrict__ Wf, const float* __restrict__ bf,
    float* __restrict__ out, int G)
{
    __shared__ float xs[256];
    __shared__ float red[128];
    int g = blockIdx.x;
    int t = threadIdx.x;   // 0..127
    for (int i = t; i < 256; i += 128) xs[i] = bf2f(x1[(long)g * 256 + i]);
    __syncthreads();
    float acc = bh[t];
    for (int k = 0; k < 256; ++k)
        acc = fmaf(xs[k], Wh[(long)k * 128 + t], acc);
    acc = acc > 0.f ? acc : 0.01f * acc;   // jax leaky_relu default slope
    red[t] = acc * Wf[t];
    __syncthreads();
    for (int s = 64; s > 0; s >>= 1) {
        if (t < s) red[t] += red[t + s];
        __syncthreads();
    }
    if (t == 0) out[g] = red[0] + bf[0];   // f32 store — output dtype is float32
}

extern "C" void kernel_launch(void* const* d_in, const int* in_sizes, int n_in,
                              void* d_out, int out_size, void* d_ws, size_t ws_size,
                              hipStream_t stream)
{
    const int* an   = (const int*)d_in[0];
    const int* ct   = (const int*)d_in[1];
    const int* bt   = (const int*)d_in[2];
    const int* bd   = (const int*)d_in[3];
    const int* src  = (const int*)d_in[4];
    const int* dst  = (const int*)d_in[5];
    const int* gid  = (const int*)d_in[6];
    const float* emb_atom  = (const float*)d_in[8];
    const float* emb_chir  = (const float*)d_in[9];
    const float* edge_bond = (const float*)d_in[10];
    const float* edge_dir  = (const float*)d_in[11];
    const float* W1   = (const float*)d_in[12];
    const float* b1   = (const float*)d_in[13];
    const float* W2   = (const float*)d_in[14];
    const float* b2   = (const float*)d_in[15];
    const float* bn_g = (const float*)d_in[16];
    const float* bn_b = (const float*)d_in[17];
    const float* bn_m = (const float*)d_in[18];
    const float* bn_v = (const float*)d_in[19];
    const float* Wt   = (const float*)d_in[20];
    const float* btr  = (const float*)d_in[21];
    const float* Wh   = (const float*)d_in[22];
    const float* bh   = (const float*)d_in[23];
    const float* Wf   = (const float*)d_in[24];
    const float* bf   = (const float*)d_in[25];

    const long N = in_sizes[0];
    const long E = in_sizes[4];
    const int  G = NG;

    // workspace (bytes): h bf16 120,000,000 | z bf16 120,000,000 |
    //                    tch bf16 9,830,400 | x1 bf16 4,194,304   -> 254,024,704 total
    u16* h   = (u16*)d_ws;
    u16* z   = h + N * D_NODE;
    u16* tch = z + N * D_NODE;
    u16* x1  = tch + (long)CHUNK * DHID;

    const long nodeTot = N * 75;
    const long edgeTot = E * 75;
    const int  blk = 256;
    const long nodeBlocks = (nodeTot + blk - 1) / blk;
    const long edgeBlocks = (edgeTot + blk - 1) / blk;
    const long n8 = N * D_NODE / 4;   // 64-bit words in h/z

    embed_kernel<<<nodeBlocks, blk, 0, stream>>>(an, ct, emb_atom, emb_chir, h, nodeTot);

    for (int l = 0; l < NLAYER; ++l) {
        zcopy_kernel<<<(n8 + blk - 1) / blk, blk, 0, stream>>>((const u64*)h, (u64*)z, n8);
        edge_scatter<<<edgeBlocks, blk, 0, stream>>>(
            h, src, dst, bt, bd,
            edge_bond + (long)l * 6 * D_NODE,
            edge_dir  + (long)l * 3 * D_NODE,
            z, edgeTot);

        for (long c0 = 0; c0 < N; c0 += CHUNK) {
            int rows = (int)((N - c0 < CHUNK) ? (N - c0) : CHUNK);
            dim3 g1((DHID + 63) / 64, (unsigned)((rows + 63) / 64));
            gemm_fused<0><<<g1, 256, 0, stream>>>(
                z + c0 * D_NODE,
                W1 + (long)l * D_NODE * DHID, b1 + (long)l * DHID,
                nullptr, nullptr, nullptr, nullptr,
                tch, rows, D_NODE, DHID, 1);

            dim3 g2((D_NODE + 63) / 64, (unsigned)((rows + 63) / 64));
            gemm_fused<1><<<g2, 256, 0, stream>>>(
                tch,
                W2 + (long)l * DHID * D_NODE, b2 + (long)l * D_NODE,
                bn_g + (long)l * D_NODE, bn_b + (long)l * D_NODE,
                bn_m + (long)l * D_NODE, bn_v + (long)l * D_NODE,
                h + c0 * D_NODE, rows, DHID, D_NODE, (l < NLAYER - 1) ? 1 : 0);
        }
    }

    pool_head1<<<G, 256, 0, stream>>>(h, gid, (int)N, Wt, btr, x1);
    head2_kernel<<<G, 128, 0, stream>>>(x1, Wh, bh, Wf, bf, (float*)d_out, G);
}

// Round 8
// 10545.026 us; speedup vs baseline: 2.6772x; 2.6772x over previous
//
#include <hip/hip_runtime.h>
#include <hip/hip_bf16.h>

#define D_NODE 300
#define DHID   600
#define NLAYER 5
#define NG     8192
#define BN_EPS 1e-5f
#define KP1    320      // padded K for GEMM1 (300 -> 320)
#define KP2    608      // padded K for GEMM2 (600 -> 608)
#define PER1   (DHID * KP1)    // 600*320 u16 per W1 plane
#define PER2   (D_NODE * KP2)  // 300*608 u16 per W2 plane

typedef unsigned short u16;
typedef unsigned long long u64;
using f32x4   = __attribute__((ext_vector_type(4))) float;
using short8  = __attribute__((ext_vector_type(8))) short;
using short4v = __attribute__((ext_vector_type(4))) short;

// ---- bf16 helpers (RNE) ----
__device__ __forceinline__ float bf2f(u16 u) {
    union { unsigned int i; float f; } v; v.i = ((unsigned int)u) << 16; return v.f;
}
__device__ __forceinline__ u16 f2bf(float f) {
    union { float f; unsigned int i; } v; v.f = f;
    unsigned int x = v.i;
    return (u16)((x + 0x7FFFu + ((x >> 16) & 1u)) >> 16);
}

// ---------------- embed: h(bf16) = emb_atom[an] + emb_chir[ct] ----------------
__global__ __launch_bounds__(256) void embed_kernel(
    const int* __restrict__ an, const int* __restrict__ ct,
    const float* __restrict__ emb_atom, const float* __restrict__ emb_chir,
    u16* __restrict__ h, long total)
{
    long idx = (long)blockIdx.x * blockDim.x + threadIdx.x;
    if (idx >= total) return;
    int n = (int)(idx / 75);
    int c = (int)(idx % 75);
    int a = an[n], cc = ct[n];
    const float4 av = *(const float4*)&emb_atom[(long)a * D_NODE + c * 4];
    const float4 cv = *(const float4*)&emb_chir[(long)cc * D_NODE + c * 4];
    ushort4 o;
    o.x = f2bf(av.x + cv.x);
    o.y = f2bf(av.y + cv.y);
    o.z = f2bf(av.z + cv.z);
    o.w = f2bf(av.w + cv.w);
    *(ushort4*)&h[(long)n * D_NODE + c * 4] = o;
}

// ---- weight convert+split: plane layout [L][2][N][KP]; hi = bf16(W), lo = bf16(W - hi) ----
__global__ __launch_bounds__(256) void wconv_split(
    const float* __restrict__ W, u16* __restrict__ WbT,
    int K, int N, int KP, long per, long total)
{
    long idx = (long)blockIdx.x * blockDim.x + threadIdx.x;
    if (idx >= total) return;
    int l = (int)(idx / per);
    long r = idx % per;
    int n = (int)(r / KP);
    int k = (int)(r % KP);
    float v = (k < K) ? W[(long)l * K * N + (long)k * N + n] : 0.f;
    u16 hi = f2bf(v);
    float lo = v - bf2f(hi);
    WbT[(long)(2 * l) * per + r]     = hi;
    WbT[(long)(2 * l + 1) * per + r] = f2bf(lo);
}

// ---------------- CSR build ----------------
__global__ __launch_bounds__(256) void zero_int_kernel(int* __restrict__ p, int n)
{
    int i = blockIdx.x * blockDim.x + threadIdx.x;
    if (i < n) p[i] = 0;
}
__global__ __launch_bounds__(256) void count_kernel(
    const int* __restrict__ dst, int* __restrict__ cnt, int E)
{
    int e = blockIdx.x * blockDim.x + threadIdx.x;
    if (e < E) atomicAdd(&cnt[dst[e]], 1);
}
__global__ __launch_bounds__(256) void scan1_kernel(
    const int* __restrict__ cnt, int* __restrict__ bsum, int N)
{
    __shared__ int red[256];
    int b = blockIdx.x, t = threadIdx.x;
    int i0 = b * 1024 + t * 4;
    int s = 0;
    #pragma unroll
    for (int j = 0; j < 4; ++j) { int i = i0 + j; if (i < N) s += cnt[i]; }
    red[t] = s; __syncthreads();
    for (int off = 128; off > 0; off >>= 1) {
        if (t < off) red[t] += red[t + off];
        __syncthreads();
    }
    if (t == 0) bsum[b] = red[0];
}
__global__ void scan2_kernel(int* __restrict__ bsum, int nb)
{
    if (threadIdx.x == 0 && blockIdx.x == 0) {
        int run = 0;
        for (int b = 0; b < nb; ++b) { int v = bsum[b]; bsum[b] = run; run += v; }
    }
}
__global__ __launch_bounds__(256) void scan3_kernel(
    const int* __restrict__ bsum, int* __restrict__ cnt,
    int* __restrict__ row_ptr, int N, int E)
{
    __shared__ int sbuf[256];
    int b = blockIdx.x, t = threadIdx.x;
    int i0 = b * 1024 + t * 4;
    int v[4]; int s = 0;
    #pragma unroll
    for (int j = 0; j < 4; ++j) { int i = i0 + j; v[j] = (i < N) ? cnt[i] : 0; s += v[j]; }
    sbuf[t] = s; __syncthreads();
    for (int off = 1; off < 256; off <<= 1) {
        int add = (t >= off) ? sbuf[t - off] : 0;
        __syncthreads();
        sbuf[t] += add;
        __syncthreads();
    }
    int base = bsum[b] + sbuf[t] - s;
    #pragma unroll
    for (int j = 0; j < 4; ++j) {
        int i = i0 + j;
        if (i < N) { row_ptr[i] = base; cnt[i] = base; base += v[j]; }
    }
    if (b == 0 && t == 0) row_ptr[N] = E;
}
__global__ __launch_bounds__(256) void fill_kernel(
    const int* __restrict__ dst, int* __restrict__ fillp,
    int* __restrict__ eidx, int E)
{
    int e = blockIdx.x * blockDim.x + threadIdx.x;
    if (e < E) {
        int pos = atomicAdd(&fillp[dst[e]], 1);
        eidx[pos] = e;
    }
}

// ---------------- agg (gather): z[n] = h[n] + sum_in-edges (h[src]+eb+ed), f32 accum ----------------
__global__ __launch_bounds__(256) void agg_kernel(
    const u16* __restrict__ h,
    const int* __restrict__ src, const int* __restrict__ bt, const int* __restrict__ bd,
    const int* __restrict__ row_ptr, const int* __restrict__ eidx,
    const float* __restrict__ ebond, const float* __restrict__ edir,
    u16* __restrict__ z, long total)
{
    long idx = (long)blockIdx.x * blockDim.x + threadIdx.x;
    if (idx >= total) return;
    int n = (int)(idx / 75);
    int c = (int)(idx % 75);
    const ushort4 hq = *(const ushort4*)&h[(long)n * D_NODE + c * 4];
    float a0 = bf2f(hq.x), a1 = bf2f(hq.y), a2 = bf2f(hq.z), a3 = bf2f(hq.w);
    int s0 = row_ptr[n], s1 = row_ptr[n + 1];
    for (int i = s0; i < s1; ++i) {
        int e = eidx[i];
        int s = src[e], b = bt[e], d = bd[e];
        const ushort4 hv = *(const ushort4*)&h[(long)s * D_NODE + c * 4];
        const float4 eb = *(const float4*)&ebond[(long)b * D_NODE + c * 4];
        const float4 ed = *(const float4*)&edir[(long)d * D_NODE + c * 4];
        a0 += bf2f(hv.x) + eb.x + ed.x;
        a1 += bf2f(hv.y) + eb.y + ed.y;
        a2 += bf2f(hv.z) + eb.z + ed.z;
        a3 += bf2f(hv.w) + eb.w + ed.w;
    }
    ushort4 o;
    o.x = f2bf(a0); o.y = f2bf(a1); o.z = f2bf(a2); o.w = f2bf(a3);
    *(ushort4*)&z[(long)n * D_NODE + c * 4] = o;
}

// ---------------- MFMA bf16 GEMM with split-precision W ----------------
// A: [M][K] bf16. Whi/Wlo: [N][KP] bf16 planes (W^T, K zero-padded, N exact).
// out = epilogue(A @ (Whi+Wlo)). Tile 128x64, 4 waves 2x2, K-step 32.
template<int MODE>
__global__ __launch_bounds__(256) void gemm_mfma(
    const u16* __restrict__ A,
    const u16* __restrict__ Whi, const u16* __restrict__ Wlo,
    const float* __restrict__ bias,
    const float* __restrict__ bn_g, const float* __restrict__ bn_b,
    const float* __restrict__ bn_m, const float* __restrict__ bn_v,
    u16* __restrict__ out, int M, int K, int KP, int N, int do_relu)
{
    __shared__ u16 As[128][40];   // +8 pad breaks bank conflicts on frag reads
    __shared__ u16 Bh[64][40];
    __shared__ u16 Bl[64][40];

    const int tid  = threadIdx.x;
    const int lane = tid & 63;
    const int wid  = tid >> 6;
    const int wm   = wid >> 1;
    const int wn   = wid & 1;
    const int bm   = blockIdx.y * 128;
    const int bn   = blockIdx.x * 64;
    const int lrow = lane & 15;
    const int lk   = (lane >> 4) * 8;

    f32x4 acc[4][2];
    #pragma unroll
    for (int m = 0; m < 4; ++m)
        #pragma unroll
        for (int n = 0; n < 2; ++n)
            acc[m][n] = (f32x4){0.f, 0.f, 0.f, 0.f};

    for (int k0 = 0; k0 < KP; k0 += 32) {
        #pragma unroll
        for (int p = 0; p < 4; ++p) {
            int q = p * 256 + tid;
            int row = q >> 3, u = q & 7;
            int gm = bm + row, gk = k0 + u * 4;
            short4v v = (short4v){0, 0, 0, 0};
            if (gm < M && gk < K) v = *(const short4v*)&A[(long)gm * K + gk];
            *(short4v*)&As[row][u * 4] = v;
        }
        {
            int col = tid >> 2, grp = tid & 3;
            int gn = bn + col;
            short8 vh = (short8){0,0,0,0,0,0,0,0};
            short8 vl = vh;
            if (gn < N) {
                long boff = (long)gn * KP + k0 + grp * 8;
                vh = *(const short8*)&Whi[boff];
                vl = *(const short8*)&Wlo[boff];
            }
            *(short8*)&Bh[col][grp * 8] = vh;
            *(short8*)&Bl[col][grp * 8] = vl;
        }
        __syncthreads();

        short8 a[4], bh[2], bl[2];
        #pragma unroll
        for (int m = 0; m < 4; ++m)
            a[m] = *(const short8*)&As[wm * 64 + m * 16 + lrow][lk];
        #pragma unroll
        for (int n = 0; n < 2; ++n) {
            bh[n] = *(const short8*)&Bh[wn * 32 + n * 16 + lrow][lk];
            bl[n] = *(const short8*)&Bl[wn * 32 + n * 16 + lrow][lk];
        }

        #pragma unroll
        for (int m = 0; m < 4; ++m)
            #pragma unroll
            for (int n = 0; n < 2; ++n) {
                acc[m][n] = __builtin_amdgcn_mfma_f32_16x16x32_bf16(
                    a[m], bh[n], acc[m][n], 0, 0, 0);
                acc[m][n] = __builtin_amdgcn_mfma_f32_16x16x32_bf16(
                    a[m], bl[n], acc[m][n], 0, 0, 0);
            }
        __syncthreads();
    }

    // epilogue + store (C/D: col = lane&15, row = (lane>>4)*4 + j)
    #pragma unroll
    for (int n = 0; n < 2; ++n) {
        int gn = bn + wn * 32 + n * 16 + (lane & 15);
        if (gn >= N) continue;
        float bv = bias[gn];
        float sc = 0.f, mn = 0.f, bb = 0.f;
        if (MODE == 1) {
            sc = bn_g[gn] * rsqrtf(bn_v[gn] + BN_EPS);
            mn = bn_m[gn]; bb = bn_b[gn];
        }
        #pragma unroll
        for (int m = 0; m < 4; ++m) {
            int rbase = bm + wm * 64 + m * 16 + (lane >> 4) * 4;
            #pragma unroll
            for (int j = 0; j < 4; ++j) {
                int gm = rbase + j;
                if (gm >= M) continue;
                float v = acc[m][n][j] + bv;
                if (MODE == 1) v = (v - mn) * sc + bb;
                if (do_relu) v = fmaxf(v, 0.f);
                out[(long)gm * N + gn] = f2bf(v);
            }
        }
    }
}

// ---------------- fused pool (sorted gid, binary search) + Linear(300,256) ----------------
__device__ __forceinline__ int lower_bound(const int* __restrict__ a, int n, int key)
{
    int lo = 0, hi = n;
    while (lo < hi) { int mid = (lo + hi) >> 1; if (a[mid] < key) lo = mid + 1; else hi = mid; }
    return lo;
}

__global__ __launch_bounds__(256) void pool_head1(
    const u16* __restrict__ h, const int* __restrict__ gid, int N,
    const float* __restrict__ Wt, const float* __restrict__ bt,
    float* __restrict__ x1)
{
    __shared__ float xs[304];
    __shared__ int se[2];
    int g = blockIdx.x;
    int t = threadIdx.x;
    if (t == 0) se[0] = lower_bound(gid, N, g);
    if (t == 1) se[1] = lower_bound(gid, N, g + 1);
    __syncthreads();
    int start = se[0], end = se[1];
    float inv = (end > start) ? 1.0f / (float)(end - start) : 0.f;
    float a0 = 0.f, a1 = 0.f;
    for (int n = start; n < end; ++n) {
        const u16* hp = &h[(long)n * D_NODE];
        a0 += bf2f(hp[t]);
        if (t < 44) a1 += bf2f(hp[256 + t]);
    }
    xs[t] = a0 * inv;
    if (t < 44) xs[256 + t] = a1 * inv;
    __syncthreads();
    float acc = bt[t];
    for (int k = 0; k < D_NODE; ++k)
        acc = fmaf(xs[k], Wt[(long)k * 256 + t], acc);
    x1[(long)g * 256 + t] = acc;
}

// ---------------- head part 2: Linear(256,128)+leaky, Linear(128,1), f32 out ----------------
__global__ __launch_bounds__(128) void head2_kernel(
    const float* __restrict__ x1,
    const float* __restrict__ Wh, const float* __restrict__ bh,
    const float* __restrict__ Wf, const float* __restrict__ bf,
    float* __restrict__ out, int G)
{
    __shared__ float xs[256];
    __shared__ float red[128];
    int g = blockIdx.x;
    int t = threadIdx.x;
    for (int i = t; i < 256; i += 128) xs[i] = x1[(long)g * 256 + i];
    __syncthreads();
    float acc = bh[t];
    for (int k = 0; k < 256; ++k)
        acc = fmaf(xs[k], Wh[(long)k * 128 + t], acc);
    acc = acc > 0.f ? acc : 0.01f * acc;
    red[t] = acc * Wf[t];
    __syncthreads();
    for (int s = 64; s > 0; s >>= 1) {
        if (t < s) red[t] += red[t + s];
        __syncthreads();
    }
    if (t == 0) out[g] = red[0] + bf[0];
}

extern "C" void kernel_launch(void* const* d_in, const int* in_sizes, int n_in,
                              void* d_out, int out_size, void* d_ws, size_t ws_size,
                              hipStream_t stream)
{
    const int* an   = (const int*)d_in[0];
    const int* ct   = (const int*)d_in[1];
    const int* bt   = (const int*)d_in[2];
    const int* bd   = (const int*)d_in[3];
    const int* src  = (const int*)d_in[4];
    const int* dst  = (const int*)d_in[5];
    const int* gid  = (const int*)d_in[6];
    const float* emb_atom  = (const float*)d_in[8];
    const float* emb_chir  = (const float*)d_in[9];
    const float* edge_bond = (const float*)d_in[10];
    const float* edge_dir  = (const float*)d_in[11];
    const float* W1   = (const float*)d_in[12];
    const float* b1   = (const float*)d_in[13];
    const float* W2   = (const float*)d_in[14];
    const float* b2   = (const float*)d_in[15];
    const float* bn_g = (const float*)d_in[16];
    const float* bn_b = (const float*)d_in[17];
    const float* bn_m = (const float*)d_in[18];
    const float* bn_v = (const float*)d_in[19];
    const float* Wt   = (const float*)d_in[20];
    const float* btr  = (const float*)d_in[21];
    const float* Wh   = (const float*)d_in[22];
    const float* bh   = (const float*)d_in[23];
    const float* Wf   = (const float*)d_in[24];
    const float* bf   = (const float*)d_in[25];

    const long N = in_sizes[0];
    const long E = in_sizes[4];
    const int  G = NG;

    // ---- workspace layout (fixed part ~251.5 MB; tch gets the remainder) ----
    char* base = (char*)d_ws;
    size_t off = 0;
    u16* h = (u16*)(base + off);            off += (size_t)N * D_NODE * 2;
    u16* z = (u16*)(base + off);            off += (size_t)N * D_NODE * 2;
    u16* WbT1 = (u16*)(base + off);         off += (size_t)NLAYER * 2 * PER1 * 2;
    u16* WbT2 = (u16*)(base + off);         off += (size_t)NLAYER * 2 * PER2 * 2;
    int* row_ptr = (int*)(base + off);      off += (((size_t)(N + 1) * 4) + 63) & ~(size_t)63;
    int* eidx = (int*)(base + off);         off += (((size_t)E * 4) + 63) & ~(size_t)63;
    u16* tch = (u16*)(base + off);
    long avail = (long)ws_size - (long)off;
    long chunk = (avail / (DHID * 2) / 128) * 128;   // rows of tch that fit
    if (chunk > 8192) chunk = 8192;
    if (chunk < 128)  chunk = 128;
    // aliases into z (disjoint lifetimes: CSR build pre-embed; x1 post-layers)
    int* row_fill = (int*)z;
    int* bsum     = row_fill + N;
    float* x1     = (float*)z;

    const long nodeTot = N * 75;
    const int  blk = 256;
    const long nodeBlocks = (nodeTot + blk - 1) / blk;
    const int  SB = (int)((N + 1023) / 1024);

    // ---- one-time: weights -> split bf16 (hi+lo), transposed, K-padded ----
    {
        long t1 = (long)NLAYER * PER1;
        wconv_split<<<(t1 + blk - 1) / blk, blk, 0, stream>>>(
            W1, WbT1, D_NODE, DHID, KP1, (long)PER1, t1);
        long t2 = (long)NLAYER * PER2;
        wconv_split<<<(t2 + blk - 1) / blk, blk, 0, stream>>>(
            W2, WbT2, DHID, D_NODE, KP2, (long)PER2, t2);
    }

    // ---- CSR build (graph static across layers) ----
    zero_int_kernel<<<((int)N + blk - 1) / blk, blk, 0, stream>>>(row_fill, (int)N);
    count_kernel<<<((int)E + blk - 1) / blk, blk, 0, stream>>>(dst, row_fill, (int)E);
    scan1_kernel<<<SB, blk, 0, stream>>>(row_fill, bsum, (int)N);
    scan2_kernel<<<1, 64, 0, stream>>>(bsum, SB);
    scan3_kernel<<<SB, blk, 0, stream>>>(bsum, row_fill, row_ptr, (int)N, (int)E);
    fill_kernel<<<((int)E + blk - 1) / blk, blk, 0, stream>>>(dst, row_fill, eidx, (int)E);

    embed_kernel<<<nodeBlocks, blk, 0, stream>>>(an, ct, emb_atom, emb_chir, h, nodeTot);

    for (int l = 0; l < NLAYER; ++l) {
        agg_kernel<<<nodeBlocks, blk, 0, stream>>>(
            h, src, bt, bd, row_ptr, eidx,
            edge_bond + (long)l * 6 * D_NODE,
            edge_dir  + (long)l * 3 * D_NODE,
            z, nodeTot);

        const u16* w1hi = WbT1 + (long)(2 * l) * PER1;
        const u16* w2hi = WbT2 + (long)(2 * l) * PER2;
        for (long c0 = 0; c0 < N; c0 += chunk) {
            int rows = (int)((N - c0 < chunk) ? (N - c0) : chunk);
            dim3 g1((DHID + 63) / 64, (rows + 127) / 128);
            gemm_mfma<0><<<g1, 256, 0, stream>>>(
                z + c0 * D_NODE, w1hi, w1hi + PER1,
                b1 + (long)l * DHID,
                nullptr, nullptr, nullptr, nullptr,
                tch, rows, D_NODE, KP1, DHID, 1);

            dim3 g2((D_NODE + 63) / 64, (rows + 127) / 128);
            gemm_mfma<1><<<g2, 256, 0, stream>>>(
                tch, w2hi, w2hi + PER2,
                b2 + (long)l * D_NODE,
                bn_g + (long)l * D_NODE, bn_b + (long)l * D_NODE,
                bn_m + (long)l * D_NODE, bn_v + (long)l * D_NODE,
                h + c0 * D_NODE, rows, DHID, KP2, D_NODE, (l < NLAYER - 1) ? 1 : 0);
        }
    }

    pool_head1<<<G, 256, 0, stream>>>(h, gid, (int)N, Wt, btr, x1);
    head2_kernel<<<G, 128, 0, stream>>>(x1, Wh, bh, Wf, bf, (float*)d_out, G);
}

// Round 9
// 4865.982 us; speedup vs baseline: 5.8018x; 2.1671x over previous
//
#include <hip/hip_runtime.h>
#include <hip/hip_bf16.h>

#define D_NODE 300
#define DHID   600
#define NLAYER 5
#define NG     8192
#define BN_EPS 1e-5f
#define KP1    320      // padded K for GEMM1 (300 -> 320)
#define KP2    608      // padded K for GEMM2 (600 -> 608)
#define PER1   (DHID * KP1)    // u16 per W1 plane
#define PER2   (D_NODE * KP2)  // u16 per W2 plane

typedef unsigned short u16;
typedef unsigned long long u64;
using f32x4   = __attribute__((ext_vector_type(4))) float;
using short8  = __attribute__((ext_vector_type(8))) short;
using short4v = __attribute__((ext_vector_type(4))) short;

// ---- bf16 helpers (RNE) ----
__device__ __forceinline__ float bf2f(u16 u) {
    union { unsigned int i; float f; } v; v.i = ((unsigned int)u) << 16; return v.f;
}
__device__ __forceinline__ u16 f2bf(float f) {
    union { float f; unsigned int i; } v; v.f = f;
    unsigned int x = v.i;
    return (u16)((x + 0x7FFFu + ((x >> 16) & 1u)) >> 16);
}

// ---------------- embed ----------------
__global__ __launch_bounds__(256) void embed_kernel(
    const int* __restrict__ an, const int* __restrict__ ct,
    const float* __restrict__ emb_atom, const float* __restrict__ emb_chir,
    u16* __restrict__ h, long total)
{
    long idx = (long)blockIdx.x * blockDim.x + threadIdx.x;
    if (idx >= total) return;
    int n = (int)(idx / 75);
    int c = (int)(idx % 75);
    int a = an[n], cc = ct[n];
    const float4 av = *(const float4*)&emb_atom[(long)a * D_NODE + c * 4];
    const float4 cv = *(const float4*)&emb_chir[(long)cc * D_NODE + c * 4];
    ushort4 o;
    o.x = f2bf(av.x + cv.x);
    o.y = f2bf(av.y + cv.y);
    o.z = f2bf(av.z + cv.z);
    o.w = f2bf(av.w + cv.w);
    *(ushort4*)&h[(long)n * D_NODE + c * 4] = o;
}

// ---- weight convert+split: [L][2][N][KP]; hi = bf16(W), lo = bf16(W - hi) ----
__global__ __launch_bounds__(256) void wconv_split(
    const float* __restrict__ W, u16* __restrict__ WbT,
    int K, int N, int KP, long per, long total)
{
    long idx = (long)blockIdx.x * blockDim.x + threadIdx.x;
    if (idx >= total) return;
    int l = (int)(idx / per);
    long r = idx % per;
    int n = (int)(r / KP);
    int k = (int)(r % KP);
    float v = (k < K) ? W[(long)l * K * N + (long)k * N + n] : 0.f;
    u16 hi = f2bf(v);
    float lo = v - bf2f(hi);
    WbT[(long)(2 * l) * per + r]     = hi;
    WbT[(long)(2 * l + 1) * per + r] = f2bf(lo);
}

// ---------------- CSR build ----------------
__global__ __launch_bounds__(256) void zero_int_kernel(int* __restrict__ p, int n)
{
    int i = blockIdx.x * blockDim.x + threadIdx.x;
    if (i < n) p[i] = 0;
}
__global__ __launch_bounds__(256) void count_kernel(
    const int* __restrict__ dst, int* __restrict__ cnt, int E)
{
    int e = blockIdx.x * blockDim.x + threadIdx.x;
    if (e < E) atomicAdd(&cnt[dst[e]], 1);
}
__global__ __launch_bounds__(256) void scan1_kernel(
    const int* __restrict__ cnt, int* __restrict__ bsum, int N)
{
    __shared__ int red[256];
    int b = blockIdx.x, t = threadIdx.x;
    int i0 = b * 1024 + t * 4;
    int s = 0;
    #pragma unroll
    for (int j = 0; j < 4; ++j) { int i = i0 + j; if (i < N) s += cnt[i]; }
    red[t] = s; __syncthreads();
    for (int off = 128; off > 0; off >>= 1) {
        if (t < off) red[t] += red[t + off];
        __syncthreads();
    }
    if (t == 0) bsum[b] = red[0];
}
__global__ void scan2_kernel(int* __restrict__ bsum, int nb)
{
    if (threadIdx.x == 0 && blockIdx.x == 0) {
        int run = 0;
        for (int b = 0; b < nb; ++b) { int v = bsum[b]; bsum[b] = run; run += v; }
    }
}
__global__ __launch_bounds__(256) void scan3_kernel(
    const int* __restrict__ bsum, int* __restrict__ cnt,
    int* __restrict__ row_ptr, int N, int E)
{
    __shared__ int sbuf[256];
    int b = blockIdx.x, t = threadIdx.x;
    int i0 = b * 1024 + t * 4;
    int v[4]; int s = 0;
    #pragma unroll
    for (int j = 0; j < 4; ++j) { int i = i0 + j; v[j] = (i < N) ? cnt[i] : 0; s += v[j]; }
    sbuf[t] = s; __syncthreads();
    for (int off = 1; off < 256; off <<= 1) {
        int add = (t >= off) ? sbuf[t - off] : 0;
        __syncthreads();
        sbuf[t] += add;
        __syncthreads();
    }
    int base = bsum[b] + sbuf[t] - s;
    #pragma unroll
    for (int j = 0; j < 4; ++j) {
        int i = i0 + j;
        if (i < N) { row_ptr[i] = base; cnt[i] = base; base += v[j]; }
    }
    if (b == 0 && t == 0) row_ptr[N] = E;
}
__global__ __launch_bounds__(256) void fill_kernel(
    const int* __restrict__ dst, int* __restrict__ fillp,
    int* __restrict__ eidx, int E)
{
    int e = blockIdx.x * blockDim.x + threadIdx.x;
    if (e < E) {
        int pos = atomicAdd(&fillp[dst[e]], 1);
        eidx[pos] = e;
    }
}

// ---------------- agg (gather): z[n] = h[n] + sum_in-edges (h[src]+eb+ed) ----------------
__global__ __launch_bounds__(256) void agg_kernel(
    const u16* __restrict__ h,
    const int* __restrict__ src, const int* __restrict__ bt, const int* __restrict__ bd,
    const int* __restrict__ row_ptr, const int* __restrict__ eidx,
    const float* __restrict__ ebond, const float* __restrict__ edir,
    u16* __restrict__ z, long total)
{
    long idx = (long)blockIdx.x * blockDim.x + threadIdx.x;
    if (idx >= total) return;
    int n = (int)(idx / 75);
    int c = (int)(idx % 75);
    const ushort4 hq = *(const ushort4*)&h[(long)n * D_NODE + c * 4];
    float a0 = bf2f(hq.x), a1 = bf2f(hq.y), a2 = bf2f(hq.z), a3 = bf2f(hq.w);
    int s0 = row_ptr[n], s1 = row_ptr[n + 1];
    for (int i = s0; i < s1; ++i) {
        int e = eidx[i];
        int s = src[e], b = bt[e], d = bd[e];
        const ushort4 hv = *(const ushort4*)&h[(long)s * D_NODE + c * 4];
        const float4 eb = *(const float4*)&ebond[(long)b * D_NODE + c * 4];
        const float4 ed = *(const float4*)&edir[(long)d * D_NODE + c * 4];
        a0 += bf2f(hv.x) + eb.x + ed.x;
        a1 += bf2f(hv.y) + eb.y + ed.y;
        a2 += bf2f(hv.z) + eb.z + ed.z;
        a3 += bf2f(hv.w) + eb.w + ed.w;
    }
    ushort4 o;
    o.x = f2bf(a0); o.y = f2bf(a1); o.z = f2bf(a2); o.w = f2bf(a3);
    *(ushort4*)&z[(long)n * D_NODE + c * 4] = o;
}

// ---------------- fused MLP: H = BN(relu(Z@W1+b1)@W2+b2) [+relu] ----------------
// Per block: 64 rows. Z-tile staged in LDS. T never touches HBM:
// loop 5 chunks of 128 T-cols: phase1 -> Tc(LDS, bf16), phase2 hacc += Tc@W2.
// Split-precision W (hi+lo bf16 planes) for f32-grade weights.
__global__ __launch_bounds__(256) void mlp_fused(
    const u16* __restrict__ Z,
    const u16* __restrict__ W1T,    // [600][320] hi, +PER1 lo
    const u16* __restrict__ W2T,    // [300][608] hi, +PER2 lo
    const float* __restrict__ b1, const float* __restrict__ b2,
    const float* __restrict__ bn_g, const float* __restrict__ bn_b,
    const float* __restrict__ bn_m, const float* __restrict__ bn_v,
    u16* __restrict__ Hout, int Nrows, int relu_out)
{
    __shared__ u16 As[64][328];   // 41,984 B (stride 656B -> 2-way max on frag reads)
    __shared__ u16 Tc[64][136];   // 17,408 B
    const int tid  = threadIdx.x;
    const int lane = tid & 63;
    const int w    = tid >> 6;     // wave 0..3
    const int lrow = lane & 15;
    const int kg   = lane >> 4;    // 0..3
    const long r0  = (long)blockIdx.x * 64;

    // stage Z tile: 64 rows x 320 k (zero-padded)
    for (int i = tid; i < 64 * 80; i += 256) {
        int r = i / 80, c4 = i % 80;
        short4v v = (short4v){0, 0, 0, 0};
        if (c4 < 75 && r0 + r < Nrows)
            v = *(const short4v*)&Z[(r0 + r) * D_NODE + c4 * 4];
        *(short4v*)&As[r][c4 * 4] = v;
    }
    __syncthreads();

    f32x4 hacc[4][5];
    #pragma unroll
    for (int m = 0; m < 4; ++m)
        #pragma unroll
        for (int n = 0; n < 5; ++n)
            hacc[m][n] = (f32x4){0.f, 0.f, 0.f, 0.f};

    for (int tc = 0; tc < 5; ++tc) {
        // ---- phase 1: T chunk cols [tc*128, tc*128+128); this wave: 32 cols ----
        f32x4 p1[4][2];
        #pragma unroll
        for (int m = 0; m < 4; ++m)
            #pragma unroll
            for (int n = 0; n < 2; ++n)
                p1[m][n] = (f32x4){0.f, 0.f, 0.f, 0.f};
        const int c0 = tc * 128 + w * 32;

        #pragma unroll
        for (int k0i = 0; k0i < 10; ++k0i) {
            short8 a[4];
            #pragma unroll
            for (int m = 0; m < 4; ++m)
                a[m] = *(const short8*)&As[m * 16 + lrow][k0i * 32 + kg * 8];
            #pragma unroll
            for (int nf = 0; nf < 2; ++nf) {
                int gn = c0 + nf * 16 + lrow;
                short8 bh = (short8){0,0,0,0,0,0,0,0};
                short8 bl = bh;
                if (gn < DHID) {
                    long o = (long)gn * KP1 + k0i * 32 + kg * 8;
                    bh = *(const short8*)&W1T[o];
                    bl = *(const short8*)&W1T[PER1 + o];
                }
                #pragma unroll
                for (int m = 0; m < 4; ++m) {
                    p1[m][nf] = __builtin_amdgcn_mfma_f32_16x16x32_bf16(a[m], bh, p1[m][nf], 0, 0, 0);
                    p1[m][nf] = __builtin_amdgcn_mfma_f32_16x16x32_bf16(a[m], bl, p1[m][nf], 0, 0, 0);
                }
            }
        }
        // relu + bias -> Tc (bf16). Cols with gn>=600 get 0 (zero W1/bias).
        #pragma unroll
        for (int nf = 0; nf < 2; ++nf) {
            int gn = c0 + nf * 16 + lrow;
            float bias = (gn < DHID) ? b1[gn] : 0.f;
            #pragma unroll
            for (int m = 0; m < 4; ++m)
                #pragma unroll
                for (int j = 0; j < 4; ++j) {
                    float v = fmaxf(p1[m][nf][j] + bias, 0.f);
                    Tc[m * 16 + kg * 4 + j][w * 32 + nf * 16 + lrow] = f2bf(v);
                }
        }
        __syncthreads();

        // ---- phase 2: hacc += Tc @ W2[k = tc*128 ...]; this wave: 80 out cols ----
        #pragma unroll
        for (int ks = 0; ks < 4; ++ks) {
            if (tc * 128 + ks * 32 < KP2) {   // chunk 4 has only 3 valid k-steps
                short8 a2[4];
                #pragma unroll
                for (int m = 0; m < 4; ++m)
                    a2[m] = *(const short8*)&Tc[m * 16 + lrow][ks * 32 + kg * 8];
                int gk = tc * 128 + ks * 32 + kg * 8;
                #pragma unroll
                for (int nf = 0; nf < 5; ++nf) {
                    int gn = w * 80 + nf * 16 + lrow;
                    short8 bh = (short8){0,0,0,0,0,0,0,0};
                    short8 bl = bh;
                    if (gn < D_NODE) {
                        long o = (long)gn * KP2 + gk;
                        bh = *(const short8*)&W2T[o];
                        bl = *(const short8*)&W2T[PER2 + o];
                    }
                    #pragma unroll
                    for (int m = 0; m < 4; ++m) {
                        hacc[m][nf] = __builtin_amdgcn_mfma_f32_16x16x32_bf16(a2[m], bh, hacc[m][nf], 0, 0, 0);
                        hacc[m][nf] = __builtin_amdgcn_mfma_f32_16x16x32_bf16(a2[m], bl, hacc[m][nf], 0, 0, 0);
                    }
                }
            }
        }
        __syncthreads();   // Tc consumed; next chunk may overwrite
    }

    // epilogue: bias + BN (+relu), store bf16
    #pragma unroll
    for (int nf = 0; nf < 5; ++nf) {
        int gn = w * 80 + nf * 16 + lrow;
        if (gn < D_NODE) {
            float bias = b2[gn];
            float sc = bn_g[gn] * rsqrtf(bn_v[gn] + BN_EPS);
            float mn = bn_m[gn], bb = bn_b[gn];
            #pragma unroll
            for (int m = 0; m < 4; ++m)
                #pragma unroll
                for (int j = 0; j < 4; ++j) {
                    long gr = r0 + m * 16 + kg * 4 + j;
                    if (gr < Nrows) {
                        float v = hacc[m][nf][j] + bias;
                        v = (v - mn) * sc + bb;
                        if (relu_out) v = fmaxf(v, 0.f);
                        Hout[gr * D_NODE + gn] = f2bf(v);
                    }
                }
        }
    }
}

// ---------------- fused pool (sorted gid) + Linear(300,256) ----------------
__device__ __forceinline__ int lower_bound(const int* __restrict__ a, int n, int key)
{
    int lo = 0, hi = n;
    while (lo < hi) { int mid = (lo + hi) >> 1; if (a[mid] < key) lo = mid + 1; else hi = mid; }
    return lo;
}

__global__ __launch_bounds__(256) void pool_head1(
    const u16* __restrict__ h, const int* __restrict__ gid, int N,
    const float* __restrict__ Wt, const float* __restrict__ bt,
    float* __restrict__ x1)
{
    __shared__ float xs[304];
    __shared__ int se[2];
    int g = blockIdx.x;
    int t = threadIdx.x;
    if (t == 0) se[0] = lower_bound(gid, N, g);
    if (t == 1) se[1] = lower_bound(gid, N, g + 1);
    __syncthreads();
    int start = se[0], end = se[1];
    float inv = (end > start) ? 1.0f / (float)(end - start) : 0.f;
    float a0 = 0.f, a1 = 0.f;
    for (int n = start; n < end; ++n) {
        const u16* hp = &h[(long)n * D_NODE];
        a0 += bf2f(hp[t]);
        if (t < 44) a1 += bf2f(hp[256 + t]);
    }
    xs[t] = a0 * inv;
    if (t < 44) xs[256 + t] = a1 * inv;
    __syncthreads();
    float acc = bt[t];
    for (int k = 0; k < D_NODE; ++k)
        acc = fmaf(xs[k], Wt[(long)k * 256 + t], acc);
    x1[(long)g * 256 + t] = acc;
}

// ---------------- head 2: Linear(256,128)+leaky, Linear(128,1) ----------------
__global__ __launch_bounds__(128) void head2_kernel(
    const float* __restrict__ x1,
    const float* __restrict__ Wh, const float* __restrict__ bh,
    const float* __restrict__ Wf, const float* __restrict__ bf,
    float* __restrict__ out, int G)
{
    __shared__ float xs[256];
    __shared__ float red[128];
    int g = blockIdx.x;
    int t = threadIdx.x;
    for (int i = t; i < 256; i += 128) xs[i] = x1[(long)g * 256 + i];
    __syncthreads();
    float acc = bh[t];
    for (int k = 0; k < 256; ++k)
        acc = fmaf(xs[k], Wh[(long)k * 128 + t], acc);
    acc = acc > 0.f ? acc : 0.01f * acc;
    red[t] = acc * Wf[t];
    __syncthreads();
    for (int s = 64; s > 0; s >>= 1) {
        if (t < s) red[t] += red[t + s];
        __syncthreads();
    }
    if (t == 0) out[g] = red[0] + bf[0];
}

extern "C" void kernel_launch(void* const* d_in, const int* in_sizes, int n_in,
                              void* d_out, int out_size, void* d_ws, size_t ws_size,
                              hipStream_t stream)
{
    const int* an   = (const int*)d_in[0];
    const int* ct   = (const int*)d_in[1];
    const int* bt   = (const int*)d_in[2];
    const int* bd   = (const int*)d_in[3];
    const int* src  = (const int*)d_in[4];
    const int* dst  = (const int*)d_in[5];
    const int* gid  = (const int*)d_in[6];
    const float* emb_atom  = (const float*)d_in[8];
    const float* emb_chir  = (const float*)d_in[9];
    const float* edge_bond = (const float*)d_in[10];
    const float* edge_dir  = (const float*)d_in[11];
    const float* W1   = (const float*)d_in[12];
    const float* b1   = (const float*)d_in[13];
    const float* W2   = (const float*)d_in[14];
    const float* b2   = (const float*)d_in[15];
    const float* bn_g = (const float*)d_in[16];
    const float* bn_b = (const float*)d_in[17];
    const float* bn_m = (const float*)d_in[18];
    const float* bn_v = (const float*)d_in[19];
    const float* Wt   = (const float*)d_in[20];
    const float* btr  = (const float*)d_in[21];
    const float* Wh   = (const float*)d_in[22];
    const float* bh   = (const float*)d_in[23];
    const float* Wf   = (const float*)d_in[24];
    const float* bf   = (const float*)d_in[25];

    const long N = in_sizes[0];
    const long E = in_sizes[4];
    const int  G = NG;

    // ---- workspace (~251.5 MB, fits proven >=254.0 MB) ----
    char* base = (char*)d_ws;
    size_t off = 0;
    u16* h = (u16*)(base + off);            off += (size_t)N * D_NODE * 2;
    u16* z = (u16*)(base + off);            off += (size_t)N * D_NODE * 2;
    u16* WbT1 = (u16*)(base + off);         off += (size_t)NLAYER * 2 * PER1 * 2;
    u16* WbT2 = (u16*)(base + off);         off += (size_t)NLAYER * 2 * PER2 * 2;
    int* row_ptr = (int*)(base + off);      off += (((size_t)(N + 1) * 4) + 63) & ~(size_t)63;
    int* eidx = (int*)(base + off);
    // aliases into z (disjoint lifetimes: CSR build pre-embed; x1 post-layers)
    int* row_fill = (int*)z;
    int* bsum     = row_fill + N;
    float* x1     = (float*)z;

    const long nodeTot = N * 75;
    const int  blk = 256;
    const long nodeBlocks = (nodeTot + blk - 1) / blk;
    const int  SB = (int)((N + 1023) / 1024);

    // weights -> split bf16 (hi+lo), transposed, K-padded
    {
        long t1 = (long)NLAYER * PER1;
        wconv_split<<<(t1 + blk - 1) / blk, blk, 0, stream>>>(
            W1, WbT1, D_NODE, DHID, KP1, (long)PER1, t1);
        long t2 = (long)NLAYER * PER2;
        wconv_split<<<(t2 + blk - 1) / blk, blk, 0, stream>>>(
            W2, WbT2, DHID, D_NODE, KP2, (long)PER2, t2);
    }

    // CSR build (graph static across layers)
    zero_int_kernel<<<((int)N + blk - 1) / blk, blk, 0, stream>>>(row_fill, (int)N);
    count_kernel<<<((int)E + blk - 1) / blk, blk, 0, stream>>>(dst, row_fill, (int)E);
    scan1_kernel<<<SB, blk, 0, stream>>>(row_fill, bsum, (int)N);
    scan2_kernel<<<1, 64, 0, stream>>>(bsum, SB);
    scan3_kernel<<<SB, blk, 0, stream>>>(bsum, row_fill, row_ptr, (int)N, (int)E);
    fill_kernel<<<((int)E + blk - 1) / blk, blk, 0, stream>>>(dst, row_fill, eidx, (int)E);

    embed_kernel<<<nodeBlocks, blk, 0, stream>>>(an, ct, emb_atom, emb_chir, h, nodeTot);

    const int mlpBlocks = (int)((N + 63) / 64);
    for (int l = 0; l < NLAYER; ++l) {
        agg_kernel<<<nodeBlocks, blk, 0, stream>>>(
            h, src, bt, bd, row_ptr, eidx,
            edge_bond + (long)l * 6 * D_NODE,
            edge_dir  + (long)l * 3 * D_NODE,
            z, nodeTot);

        mlp_fused<<<mlpBlocks, 256, 0, stream>>>(
            z,
            WbT1 + (long)(2 * l) * PER1,
            WbT2 + (long)(2 * l) * PER2,
            b1 + (long)l * DHID, b2 + (long)l * D_NODE,
            bn_g + (long)l * D_NODE, bn_b + (long)l * D_NODE,
            bn_m + (long)l * D_NODE, bn_v + (long)l * D_NODE,
            h, (int)N, (l < NLAYER - 1) ? 1 : 0);
    }

    pool_head1<<<G, 256, 0, stream>>>(h, gid, (int)N, Wt, btr, x1);
    head2_kernel<<<G, 128, 0, stream>>>(x1, Wh, bh, Wf, bf, (float*)d_out, G);
}

// Round 10
// 4265.801 us; speedup vs baseline: 6.6180x; 1.1407x over previous
//
#include <hip/hip_runtime.h>
#include <hip/hip_bf16.h>

#define D_NODE 300
#define DHID   600
#define NLAYER 5
#define NG     8192
#define BN_EPS 1e-5f
#define KP1    320      // padded K for GEMM1 (300 -> 320)
#define KP2    608      // padded K for GEMM2 (600 -> 608)
#define PER1   (DHID * KP1)    // u16 per W1 plane
#define PER2   (D_NODE * KP2)  // u16 per W2 plane

typedef unsigned short u16;
typedef unsigned long long u64;
using f32x4   = __attribute__((ext_vector_type(4))) float;
using short8  = __attribute__((ext_vector_type(8))) short;
using short4v = __attribute__((ext_vector_type(4))) short;

// ---- bf16 helpers (RNE) ----
__device__ __forceinline__ float bf2f(u16 u) {
    union { unsigned int i; float f; } v; v.i = ((unsigned int)u) << 16; return v.f;
}
__device__ __forceinline__ u16 f2bf(float f) {
    union { float f; unsigned int i; } v; v.f = f;
    unsigned int x = v.i;
    return (u16)((x + 0x7FFFu + ((x >> 16) & 1u)) >> 16);
}

// ---------------- embed ----------------
__global__ __launch_bounds__(256) void embed_kernel(
    const int* __restrict__ an, const int* __restrict__ ct,
    const float* __restrict__ emb_atom, const float* __restrict__ emb_chir,
    u16* __restrict__ h, long total)
{
    long idx = (long)blockIdx.x * blockDim.x + threadIdx.x;
    if (idx >= total) return;
    int n = (int)(idx / 75);
    int c = (int)(idx % 75);
    int a = an[n], cc = ct[n];
    const float4 av = *(const float4*)&emb_atom[(long)a * D_NODE + c * 4];
    const float4 cv = *(const float4*)&emb_chir[(long)cc * D_NODE + c * 4];
    ushort4 o;
    o.x = f2bf(av.x + cv.x);
    o.y = f2bf(av.y + cv.y);
    o.z = f2bf(av.z + cv.z);
    o.w = f2bf(av.w + cv.w);
    *(ushort4*)&h[(long)n * D_NODE + c * 4] = o;
}

// ---- weight convert+split: [L][2][N][KP]; hi = bf16(W), lo = bf16(W - hi) ----
__global__ __launch_bounds__(256) void wconv_split(
    const float* __restrict__ W, u16* __restrict__ WbT,
    int K, int N, int KP, long per, long total)
{
    long idx = (long)blockIdx.x * blockDim.x + threadIdx.x;
    if (idx >= total) return;
    int l = (int)(idx / per);
    long r = idx % per;
    int n = (int)(r / KP);
    int k = (int)(r % KP);
    float v = (k < K) ? W[(long)l * K * N + (long)k * N + n] : 0.f;
    u16 hi = f2bf(v);
    float lo = v - bf2f(hi);
    WbT[(long)(2 * l) * per + r]     = hi;
    WbT[(long)(2 * l + 1) * per + r] = f2bf(lo);
}

// ---------------- CSR build ----------------
__global__ __launch_bounds__(256) void zero_int_kernel(int* __restrict__ p, int n)
{
    int i = blockIdx.x * blockDim.x + threadIdx.x;
    if (i < n) p[i] = 0;
}
__global__ __launch_bounds__(256) void count_kernel(
    const int* __restrict__ dst, int* __restrict__ cnt, int E)
{
    int e = blockIdx.x * blockDim.x + threadIdx.x;
    if (e < E) atomicAdd(&cnt[dst[e]], 1);
}
__global__ __launch_bounds__(256) void scan1_kernel(
    const int* __restrict__ cnt, int* __restrict__ bsum, int N)
{
    __shared__ int red[256];
    int b = blockIdx.x, t = threadIdx.x;
    int i0 = b * 1024 + t * 4;
    int s = 0;
    #pragma unroll
    for (int j = 0; j < 4; ++j) { int i = i0 + j; if (i < N) s += cnt[i]; }
    red[t] = s; __syncthreads();
    for (int off = 128; off > 0; off >>= 1) {
        if (t < off) red[t] += red[t + off];
        __syncthreads();
    }
    if (t == 0) bsum[b] = red[0];
}
__global__ void scan2_kernel(int* __restrict__ bsum, int nb)
{
    if (threadIdx.x == 0 && blockIdx.x == 0) {
        int run = 0;
        for (int b = 0; b < nb; ++b) { int v = bsum[b]; bsum[b] = run; run += v; }
    }
}
__global__ __launch_bounds__(256) void scan3_kernel(
    const int* __restrict__ bsum, int* __restrict__ cnt,
    int* __restrict__ row_ptr, int N, int E)
{
    __shared__ int sbuf[256];
    int b = blockIdx.x, t = threadIdx.x;
    int i0 = b * 1024 + t * 4;
    int v[4]; int s = 0;
    #pragma unroll
    for (int j = 0; j < 4; ++j) { int i = i0 + j; v[j] = (i < N) ? cnt[i] : 0; s += v[j]; }
    sbuf[t] = s; __syncthreads();
    for (int off = 1; off < 256; off <<= 1) {
        int add = (t >= off) ? sbuf[t - off] : 0;
        __syncthreads();
        sbuf[t] += add;
        __syncthreads();
    }
    int base = bsum[b] + sbuf[t] - s;
    #pragma unroll
    for (int j = 0; j < 4; ++j) {
        int i = i0 + j;
        if (i < N) { row_ptr[i] = base; cnt[i] = base; base += v[j]; }
    }
    if (b == 0 && t == 0) row_ptr[N] = E;
}
__global__ __launch_bounds__(256) void fill_kernel(
    const int* __restrict__ dst, int* __restrict__ fillp,
    int* __restrict__ eidx, int E)
{
    int e = blockIdx.x * blockDim.x + threadIdx.x;
    if (e < E) {
        int pos = atomicAdd(&fillp[dst[e]], 1);
        eidx[pos] = e;
    }
}

// ---------------- agg (gather): z[n] = h[n] + sum_in-edges (h[src]+eb+ed) ----------------
__global__ __launch_bounds__(256) void agg_kernel(
    const u16* __restrict__ h,
    const int* __restrict__ src, const int* __restrict__ bt, const int* __restrict__ bd,
    const int* __restrict__ row_ptr, const int* __restrict__ eidx,
    const float* __restrict__ ebond, const float* __restrict__ edir,
    u16* __restrict__ z, long total)
{
    long idx = (long)blockIdx.x * blockDim.x + threadIdx.x;
    if (idx >= total) return;
    int n = (int)(idx / 75);
    int c = (int)(idx % 75);
    const ushort4 hq = *(const ushort4*)&h[(long)n * D_NODE + c * 4];
    float a0 = bf2f(hq.x), a1 = bf2f(hq.y), a2 = bf2f(hq.z), a3 = bf2f(hq.w);
    int s0 = row_ptr[n], s1 = row_ptr[n + 1];
    for (int i = s0; i < s1; ++i) {
        int e = eidx[i];
        int s = src[e], b = bt[e], d = bd[e];
        const ushort4 hv = *(const ushort4*)&h[(long)s * D_NODE + c * 4];
        const float4 eb = *(const float4*)&ebond[(long)b * D_NODE + c * 4];
        const float4 ed = *(const float4*)&edir[(long)d * D_NODE + c * 4];
        a0 += bf2f(hv.x) + eb.x + ed.x;
        a1 += bf2f(hv.y) + eb.y + ed.y;
        a2 += bf2f(hv.z) + eb.z + ed.z;
        a3 += bf2f(hv.w) + eb.w + ed.w;
    }
    ushort4 o;
    o.x = f2bf(a0); o.y = f2bf(a1); o.z = f2bf(a2); o.w = f2bf(a3);
    *(ushort4*)&z[(long)n * D_NODE + c * 4] = o;
}

// ---------------- fused MLP: H = BN(relu(Z@W1+b1)@W2+b2) [+relu] ----------------
// v2: explicit W register prefetch (next k-step loads issued before current MFMAs),
// hi-block-then-lo-block MFMA ordering (breaks dependent-pair stalls; per-acc
// order unchanged -> bit-identical), setprio around MFMA clusters.
__global__ __launch_bounds__(256, 2) void mlp_fused(
    const u16* __restrict__ Z,
    const u16* __restrict__ W1T,    // [600][320] hi, +PER1 lo
    const u16* __restrict__ W2T,    // [300][608] hi, +PER2 lo
    const float* __restrict__ b1, const float* __restrict__ b2,
    const float* __restrict__ bn_g, const float* __restrict__ bn_b,
    const float* __restrict__ bn_m, const float* __restrict__ bn_v,
    u16* __restrict__ Hout, int Nrows, int relu_out)
{
    __shared__ u16 As[64][328];   // 41,984 B
    __shared__ u16 Tc[64][136];   // 17,408 B
    const int tid  = threadIdx.x;
    const int lane = tid & 63;
    const int w    = tid >> 6;     // wave 0..3
    const int lrow = lane & 15;
    const int kg   = lane >> 4;    // 0..3
    const long r0  = (long)blockIdx.x * 64;
    const short8 zz = (short8){0,0,0,0,0,0,0,0};

    // stage Z tile: 64 rows x 320 k (zero-padded)
    for (int i = tid; i < 64 * 80; i += 256) {
        int r = i / 80, c4 = i % 80;
        short4v v = (short4v){0, 0, 0, 0};
        if (c4 < 75 && r0 + r < Nrows)
            v = *(const short4v*)&Z[(r0 + r) * D_NODE + c4 * 4];
        *(short4v*)&As[r][c4 * 4] = v;
    }
    __syncthreads();

    f32x4 hacc[4][5];
    #pragma unroll
    for (int m = 0; m < 4; ++m)
        #pragma unroll
        for (int n = 0; n < 5; ++n)
            hacc[m][n] = (f32x4){0.f, 0.f, 0.f, 0.f};

    for (int tc = 0; tc < 5; ++tc) {
        const int c0 = tc * 128 + w * 32;

        // ---- phase 1: T chunk cols [tc*128, +128); this wave: 32 cols ----
        const u16* w1p[2]; bool w1v[2];
        #pragma unroll
        for (int nf = 0; nf < 2; ++nf) {
            int gn = c0 + nf * 16 + lrow;
            w1v[nf] = (gn < DHID);
            w1p[nf] = W1T + (long)gn * KP1 + kg * 8;
        }
        f32x4 p1[4][2];
        #pragma unroll
        for (int m = 0; m < 4; ++m)
            #pragma unroll
            for (int n = 0; n < 2; ++n)
                p1[m][n] = (f32x4){0.f, 0.f, 0.f, 0.f};

        short8 cwh0 = w1v[0] ? *(const short8*)(w1p[0])        : zz;
        short8 cwl0 = w1v[0] ? *(const short8*)(w1p[0] + PER1) : zz;
        short8 cwh1 = w1v[1] ? *(const short8*)(w1p[1])        : zz;
        short8 cwl1 = w1v[1] ? *(const short8*)(w1p[1] + PER1) : zz;

        #pragma unroll
        for (int k0i = 0; k0i < 10; ++k0i) {
            short8 nwh0, nwl0, nwh1, nwl1;
            if (k0i < 9) {   // prefetch next k-step while this one computes
                const int ko = (k0i + 1) * 32;
                nwh0 = w1v[0] ? *(const short8*)(w1p[0] + ko)        : zz;
                nwl0 = w1v[0] ? *(const short8*)(w1p[0] + PER1 + ko) : zz;
                nwh1 = w1v[1] ? *(const short8*)(w1p[1] + ko)        : zz;
                nwl1 = w1v[1] ? *(const short8*)(w1p[1] + PER1 + ko) : zz;
            }
            short8 a0 = *(const short8*)&As[ 0 + lrow][k0i * 32 + kg * 8];
            short8 a1 = *(const short8*)&As[16 + lrow][k0i * 32 + kg * 8];
            short8 a2 = *(const short8*)&As[32 + lrow][k0i * 32 + kg * 8];
            short8 a3 = *(const short8*)&As[48 + lrow][k0i * 32 + kg * 8];

            __builtin_amdgcn_s_setprio(1);
            // all-hi (8 independent), then all-lo (deps 8 apart)
            p1[0][0] = __builtin_amdgcn_mfma_f32_16x16x32_bf16(a0, cwh0, p1[0][0], 0, 0, 0);
            p1[1][0] = __builtin_amdgcn_mfma_f32_16x16x32_bf16(a1, cwh0, p1[1][0], 0, 0, 0);
            p1[2][0] = __builtin_amdgcn_mfma_f32_16x16x32_bf16(a2, cwh0, p1[2][0], 0, 0, 0);
            p1[3][0] = __builtin_amdgcn_mfma_f32_16x16x32_bf16(a3, cwh0, p1[3][0], 0, 0, 0);
            p1[0][1] = __builtin_amdgcn_mfma_f32_16x16x32_bf16(a0, cwh1, p1[0][1], 0, 0, 0);
            p1[1][1] = __builtin_amdgcn_mfma_f32_16x16x32_bf16(a1, cwh1, p1[1][1], 0, 0, 0);
            p1[2][1] = __builtin_amdgcn_mfma_f32_16x16x32_bf16(a2, cwh1, p1[2][1], 0, 0, 0);
            p1[3][1] = __builtin_amdgcn_mfma_f32_16x16x32_bf16(a3, cwh1, p1[3][1], 0, 0, 0);
            p1[0][0] = __builtin_amdgcn_mfma_f32_16x16x32_bf16(a0, cwl0, p1[0][0], 0, 0, 0);
            p1[1][0] = __builtin_amdgcn_mfma_f32_16x16x32_bf16(a1, cwl0, p1[1][0], 0, 0, 0);
            p1[2][0] = __builtin_amdgcn_mfma_f32_16x16x32_bf16(a2, cwl0, p1[2][0], 0, 0, 0);
            p1[3][0] = __builtin_amdgcn_mfma_f32_16x16x32_bf16(a3, cwl0, p1[3][0], 0, 0, 0);
            p1[0][1] = __builtin_amdgcn_mfma_f32_16x16x32_bf16(a0, cwl1, p1[0][1], 0, 0, 0);
            p1[1][1] = __builtin_amdgcn_mfma_f32_16x16x32_bf16(a1, cwl1, p1[1][1], 0, 0, 0);
            p1[2][1] = __builtin_amdgcn_mfma_f32_16x16x32_bf16(a2, cwl1, p1[2][1], 0, 0, 0);
            p1[3][1] = __builtin_amdgcn_mfma_f32_16x16x32_bf16(a3, cwl1, p1[3][1], 0, 0, 0);
            __builtin_amdgcn_s_setprio(0);

            if (k0i < 9) { cwh0 = nwh0; cwl0 = nwl0; cwh1 = nwh1; cwl1 = nwl1; }
        }

        // relu + bias -> Tc (bf16). Cols with gn>=600 get 0 (zero W1/bias).
        #pragma unroll
        for (int nf = 0; nf < 2; ++nf) {
            int gn = c0 + nf * 16 + lrow;
            float bias = (gn < DHID) ? b1[gn] : 0.f;
            #pragma unroll
            for (int m = 0; m < 4; ++m)
                #pragma unroll
                for (int j = 0; j < 4; ++j) {
                    float v = fmaxf(p1[m][nf][j] + bias, 0.f);
                    Tc[m * 16 + kg * 4 + j][w * 32 + nf * 16 + lrow] = f2bf(v);
                }
        }
        __syncthreads();

        // ---- phase 2: hacc += Tc @ W2[k = tc*128 ...]; this wave: 80 out cols ----
        const u16* w2p[5]; bool w2v[5];
        #pragma unroll
        for (int nf = 0; nf < 5; ++nf) {
            int gn = w * 80 + nf * 16 + lrow;
            w2v[nf] = (gn < D_NODE);
            w2p[nf] = W2T + (long)gn * KP2 + tc * 128 + kg * 8;
        }
        short8 w2h[5], w2l[5];
        #pragma unroll
        for (int nf = 0; nf < 5; ++nf) {
            w2h[nf] = w2v[nf] ? *(const short8*)(w2p[nf])        : zz;
            w2l[nf] = w2v[nf] ? *(const short8*)(w2p[nf] + PER2) : zz;
        }

        #pragma unroll
        for (int ks = 0; ks < 4; ++ks) {
            short8 w2hn[5], w2ln[5];
            if (ks < 3) {     // prefetch next ks
                const int ko = (ks + 1) * 32;
                const bool nv = (tc < 4) || (ks < 2);
                #pragma unroll
                for (int nf = 0; nf < 5; ++nf) {
                    w2hn[nf] = (nv && w2v[nf]) ? *(const short8*)(w2p[nf] + ko)        : zz;
                    w2ln[nf] = (nv && w2v[nf]) ? *(const short8*)(w2p[nf] + PER2 + ko) : zz;
                }
            }
            if ((tc < 4) || (ks < 3)) {    // current k-step valid (k < 608)
                short8 t0 = *(const short8*)&Tc[ 0 + lrow][ks * 32 + kg * 8];
                short8 t1 = *(const short8*)&Tc[16 + lrow][ks * 32 + kg * 8];
                short8 t2 = *(const short8*)&Tc[32 + lrow][ks * 32 + kg * 8];
                short8 t3 = *(const short8*)&Tc[48 + lrow][ks * 32 + kg * 8];
                __builtin_amdgcn_s_setprio(1);
                #pragma unroll
                for (int nf = 0; nf < 5; ++nf) {
                    hacc[0][nf] = __builtin_amdgcn_mfma_f32_16x16x32_bf16(t0, w2h[nf], hacc[0][nf], 0, 0, 0);
                    hacc[1][nf] = __builtin_amdgcn_mfma_f32_16x16x32_bf16(t1, w2h[nf], hacc[1][nf], 0, 0, 0);
                    hacc[2][nf] = __builtin_amdgcn_mfma_f32_16x16x32_bf16(t2, w2h[nf], hacc[2][nf], 0, 0, 0);
                    hacc[3][nf] = __builtin_amdgcn_mfma_f32_16x16x32_bf16(t3, w2h[nf], hacc[3][nf], 0, 0, 0);
                }
                #pragma unroll
                for (int nf = 0; nf < 5; ++nf) {
                    hacc[0][nf] = __builtin_amdgcn_mfma_f32_16x16x32_bf16(t0, w2l[nf], hacc[0][nf], 0, 0, 0);
                    hacc[1][nf] = __builtin_amdgcn_mfma_f32_16x16x32_bf16(t1, w2l[nf], hacc[1][nf], 0, 0, 0);
                    hacc[2][nf] = __builtin_amdgcn_mfma_f32_16x16x32_bf16(t2, w2l[nf], hacc[2][nf], 0, 0, 0);
                    hacc[3][nf] = __builtin_amdgcn_mfma_f32_16x16x32_bf16(t3, w2l[nf], hacc[3][nf], 0, 0, 0);
                }
                __builtin_amdgcn_s_setprio(0);
            }
            if (ks < 3) {
                #pragma unroll
                for (int nf = 0; nf < 5; ++nf) { w2h[nf] = w2hn[nf]; w2l[nf] = w2ln[nf]; }
            }
        }
        __syncthreads();   // Tc consumed; next chunk may overwrite
    }

    // epilogue: bias + BN (+relu), store bf16
    #pragma unroll
    for (int nf = 0; nf < 5; ++nf) {
        int gn = w * 80 + nf * 16 + lrow;
        if (gn < D_NODE) {
            float bias = b2[gn];
            float sc = bn_g[gn] * rsqrtf(bn_v[gn] + BN_EPS);
            float mn = bn_m[gn], bb = bn_b[gn];
            #pragma unroll
            for (int m = 0; m < 4; ++m)
                #pragma unroll
                for (int j = 0; j < 4; ++j) {
                    long gr = r0 + m * 16 + kg * 4 + j;
                    if (gr < Nrows) {
                        float v = hacc[m][nf][j] + bias;
                        v = (v - mn) * sc + bb;
                        if (relu_out) v = fmaxf(v, 0.f);
                        Hout[gr * D_NODE + gn] = f2bf(v);
                    }
                }
        }
    }
}

// ---------------- fused pool (sorted gid) + Linear(300,256) ----------------
__device__ __forceinline__ int lower_bound(const int* __restrict__ a, int n, int key)
{
    int lo = 0, hi = n;
    while (lo < hi) { int mid = (lo + hi) >> 1; if (a[mid] < key) lo = mid + 1; else hi = mid; }
    return lo;
}

__global__ __launch_bounds__(256) void pool_head1(
    const u16* __restrict__ h, const int* __restrict__ gid, int N,
    const float* __restrict__ Wt, const float* __restrict__ bt,
    float* __restrict__ x1)
{
    __shared__ float xs[304];
    __shared__ int se[2];
    int g = blockIdx.x;
    int t = threadIdx.x;
    if (t == 0) se[0] = lower_bound(gid, N, g);
    if (t == 1) se[1] = lower_bound(gid, N, g + 1);
    __syncthreads();
    int start = se[0], end = se[1];
    float inv = (end > start) ? 1.0f / (float)(end - start) : 0.f;
    float a0 = 0.f, a1 = 0.f;
    for (int n = start; n < end; ++n) {
        const u16* hp = &h[(long)n * D_NODE];
        a0 += bf2f(hp[t]);
        if (t < 44) a1 += bf2f(hp[256 + t]);
    }
    xs[t] = a0 * inv;
    if (t < 44) xs[256 + t] = a1 * inv;
    __syncthreads();
    float acc = bt[t];
    for (int k = 0; k < D_NODE; ++k)
        acc = fmaf(xs[k], Wt[(long)k * 256 + t], acc);
    x1[(long)g * 256 + t] = acc;
}

// ---------------- head 2: Linear(256,128)+leaky, Linear(128,1) ----------------
__global__ __launch_bounds__(128) void head2_kernel(
    const float* __restrict__ x1,
    const float* __restrict__ Wh, const float* __restrict__ bh,
    const float* __restrict__ Wf, const float* __restrict__ bf,
    float* __restrict__ out, int G)
{
    __shared__ float xs[256];
    __shared__ float red[128];
    int g = blockIdx.x;
    int t = threadIdx.x;
    for (int i = t; i < 256; i += 128) xs[i] = x1[(long)g * 256 + i];
    __syncthreads();
    float acc = bh[t];
    for (int k = 0; k < 256; ++k)
        acc = fmaf(xs[k], Wh[(long)k * 128 + t], acc);
    acc = acc > 0.f ? acc : 0.01f * acc;
    red[t] = acc * Wf[t];
    __syncthreads();
    for (int s = 64; s > 0; s >>= 1) {
        if (t < s) red[t] += red[t + s];
        __syncthreads();
    }
    if (t == 0) out[g] = red[0] + bf[0];
}

extern "C" void kernel_launch(void* const* d_in, const int* in_sizes, int n_in,
                              void* d_out, int out_size, void* d_ws, size_t ws_size,
                              hipStream_t stream)
{
    const int* an   = (const int*)d_in[0];
    const int* ct   = (const int*)d_in[1];
    const int* bt   = (const int*)d_in[2];
    const int* bd   = (const int*)d_in[3];
    const int* src  = (const int*)d_in[4];
    const int* dst  = (const int*)d_in[5];
    const int* gid  = (const int*)d_in[6];
    const float* emb_atom  = (const float*)d_in[8];
    const float* emb_chir  = (const float*)d_in[9];
    const float* edge_bond = (const float*)d_in[10];
    const float* edge_dir  = (const float*)d_in[11];
    const float* W1   = (const float*)d_in[12];
    const float* b1   = (const float*)d_in[13];
    const float* W2   = (const float*)d_in[14];
    const float* b2   = (const float*)d_in[15];
    const float* bn_g = (const float*)d_in[16];
    const float* bn_b = (const float*)d_in[17];
    const float* bn_m = (const float*)d_in[18];
    const float* bn_v = (const float*)d_in[19];
    const float* Wt   = (const float*)d_in[20];
    const float* btr  = (const float*)d_in[21];
    const float* Wh   = (const float*)d_in[22];
    const float* bh   = (const float*)d_in[23];
    const float* Wf   = (const float*)d_in[24];
    const float* bf   = (const float*)d_in[25];

    const long N = in_sizes[0];
    const long E = in_sizes[4];
    const int  G = NG;

    // ---- workspace (~251.5 MB) ----
    char* base = (char*)d_ws;
    size_t off = 0;
    u16* h = (u16*)(base + off);            off += (size_t)N * D_NODE * 2;
    u16* z = (u16*)(base + off);            off += (size_t)N * D_NODE * 2;
    u16* WbT1 = (u16*)(base + off);         off += (size_t)NLAYER * 2 * PER1 * 2;
    u16* WbT2 = (u16*)(base + off);         off += (size_t)NLAYER * 2 * PER2 * 2;
    int* row_ptr = (int*)(base + off);      off += (((size_t)(N + 1) * 4) + 63) & ~(size_t)63;
    int* eidx = (int*)(base + off);
    // aliases into z (disjoint lifetimes: CSR build pre-embed; x1 post-layers)
    int* row_fill = (int*)z;
    int* bsum     = row_fill + N;
    float* x1     = (float*)z;

    const long nodeTot = N * 75;
    const int  blk = 256;
    const long nodeBlocks = (nodeTot + blk - 1) / blk;
    const int  SB = (int)((N + 1023) / 1024);

    // weights -> split bf16 (hi+lo), transposed, K-padded
    {
        long t1 = (long)NLAYER * PER1;
        wconv_split<<<(t1 + blk - 1) / blk, blk, 0, stream>>>(
            W1, WbT1, D_NODE, DHID, KP1, (long)PER1, t1);
        long t2 = (long)NLAYER * PER2;
        wconv_split<<<(t2 + blk - 1) / blk, blk, 0, stream>>>(
            W2, WbT2, DHID, D_NODE, KP2, (long)PER2, t2);
    }

    // CSR build (graph static across layers)
    zero_int_kernel<<<((int)N + blk - 1) / blk, blk, 0, stream>>>(row_fill, (int)N);
    count_kernel<<<((int)E + blk - 1) / blk, blk, 0, stream>>>(dst, row_fill, (int)E);
    scan1_kernel<<<SB, blk, 0, stream>>>(row_fill, bsum, (int)N);
    scan2_kernel<<<1, 64, 0, stream>>>(bsum, SB);
    scan3_kernel<<<SB, blk, 0, stream>>>(bsum, row_fill, row_ptr, (int)N, (int)E);
    fill_kernel<<<((int)E + blk - 1) / blk, blk, 0, stream>>>(dst, row_fill, eidx, (int)E);

    embed_kernel<<<nodeBlocks, blk, 0, stream>>>(an, ct, emb_atom, emb_chir, h, nodeTot);

    const int mlpBlocks = (int)((N + 63) / 64);
    for (int l = 0; l < NLAYER; ++l) {
        agg_kernel<<<nodeBlocks, blk, 0, stream>>>(
            h, src, bt, bd, row_ptr, eidx,
            edge_bond + (long)l * 6 * D_NODE,
            edge_dir  + (long)l * 3 * D_NODE,
            z, nodeTot);

        mlp_fused<<<mlpBlocks, 256, 0, stream>>>(
            z,
            WbT1 + (long)(2 * l) * PER1,
            WbT2 + (long)(2 * l) * PER2,
            b1 + (long)l * DHID, b2 + (long)l * D_NODE,
            bn_g + (long)l * D_NODE, bn_b + (long)l * D_NODE,
            bn_m + (long)l * D_NODE, bn_v + (long)l * D_NODE,
            h, (int)N, (l < NLAYER - 1) ? 1 : 0);
    }

    pool_head1<<<G, 256, 0, stream>>>(h, gid, (int)N, Wt, btr, x1);
    head2_kernel<<<G, 128, 0, stream>>>(x1, Wh, bh, Wf, bf, (float*)d_out, G);
}